// Round 10
// baseline (3437.630 us; speedup 1.0000x reference)
//
#include <hip/hip_runtime.h>
#include <cmath>

#define HH   128
#define G3   384
#define TT   512
#define BTOT 512
#define BB   2
#define WT   32                // window length staged per X-phase
#define NBLK (BTOT / BB)       // 256 blocks = 1 per CU
#define NTHR 512               // 8 waves, 2/SIMD, 256-VGPR budget

__device__ __forceinline__ float sigmoidf_(float x) {
    return 1.0f / (1.0f + __expf(-x));
}
__device__ __forceinline__ float tanhf_(float x) {
    float e = __expf(2.0f * x);
    return 1.0f - 2.0f / (e + 1.0f);
}
// lgkmcnt(0)-only barrier: LDS writes visible; vmem (global stores/loads) stay in flight
__device__ __forceinline__ void lds_barrier() {
    asm volatile("s_waitcnt lgkmcnt(0)" ::: "memory");
    __builtin_amdgcn_s_barrier();
}

// One GRU layer, one kernel. kt=tid&3 owns a 32-wide k-slice of Whh rows
// {j,128+j,256+j} (j=gt=tid>>2): ONLY these 96 floats are register-resident
// (low pressure -> arch VGPRs, no AGPR copy bloat). The x-part is computed in
// a windowed GEMM every WT steps: 32 tokens staged in LDS, Wih streamed from
// L2 (196 KB/window/block, amortized), results to s_xi. Recurrent step reads
// h + xi from LDS, 1 lgkm barrier/step, h double-buffered in padded LDS.
template <bool FIRST, bool LAST>
__global__ __launch_bounds__(NTHR, 2) void gru_layer(
    const float* in, float* out,   // mid layers alias (in-place): NO __restrict__
    const float* __restrict__ Wih, const float* __restrict__ Whh,
    const float* __restrict__ bih, const float* __restrict__ bhh,
    const float* __restrict__ fcw, const float* __restrict__ fcb,
    float* __restrict__ fcout) {
    const int tid = threadIdx.x;
    const int kt  = tid & 3;
    const int gt  = tid >> 2;          // hidden unit j in [0,128)
    const int b0  = blockIdx.x * BB;

    // h slices padded to 36 floats: kt-slice -> bank quad 4kt (conflict-free b128)
    __shared__ __align__(16) float s_h[2][BB][4][36];
    // FIRST: whole x sequence for both rows (2*512*5). Mid: window input tokens.
    __shared__ __align__(16) float s_in[FIRST ? (BB * TT * 5) : (BB * WT * HH)];
    // Mid: window xi results (2*32*384). FIRST: dummy.
    __shared__ __align__(16) float s_xi[FIRST ? 4 : (BB * WT * G3)];

    // ---- recurrent weights: rows {gt,128+gt,256+gt}, k-slice kt*32, pinned ----
    float wh[3][32];
#pragma unroll
    for (int i = 0; i < 3; ++i) {
        const float* wr = Whh + (size_t)(i * HH + gt) * HH + kt * 32;
#pragma unroll
        for (int j = 0; j < 32; j += 4) {
            float4 v = *(const float4*)(wr + j);
            wh[i][j] = v.x; wh[i][j + 1] = v.y; wh[i][j + 2] = v.z; wh[i][j + 3] = v.w;
        }
    }
#pragma unroll
    for (int i = 0; i < 3; ++i)
#pragma unroll
        for (int j = 0; j < 32; ++j) asm volatile("" : "+v"(wh[i][j]));

    float wx5[3][5];
    if constexpr (FIRST) {
#pragma unroll
        for (int i = 0; i < 3; ++i)
#pragma unroll
            for (int j = 0; j < 5; ++j) wx5[i][j] = Wih[(i * HH + gt) * 5 + j];
    }

    const float br  = bih[gt] + bhh[gt];
    const float bz  = bih[HH + gt] + bhh[HH + gt];
    const float bxn = bih[2 * HH + gt];
    const float bhn = bhh[2 * HH + gt];

    if (tid < BB * HH) {
        int bb = tid >> 7, j = tid & (HH - 1);
        s_h[0][bb][j >> 5][j & 31] = 0.0f;
    }
    if constexpr (FIRST) {
        // stage the entire 2-row x sequence once: 5120 floats, coalesced
#pragma unroll
        for (int r = 0; r < (BB * TT * 5) / NTHR; ++r) {
            int idx = r * NTHR + tid;
            s_in[idx] = in[(size_t)b0 * TT * 5 + idx];
        }
    }
    __syncthreads();

    for (int w = 0; w < TT / WT; ++w) {
        if constexpr (!FIRST) {
            // re-pin wh at window granularity (discourages AGPR demotion)
#pragma unroll
            for (int i = 0; i < 3; ++i)
#pragma unroll
                for (int j = 0; j < 32; ++j) asm volatile("" : "+v"(wh[i][j]));

            // ---- stage window input: 2 rows x 32 tok x 128 = 2048 float4 ----
            {
                const size_t gbase = (size_t)b0 * TT * HH + (size_t)w * WT * HH;
#pragma unroll
                for (int r = 0; r < 4; ++r) {
                    int idx = r * NTHR + tid;           // float4 idx in [0,2048)
                    int bb  = idx >> 10;
                    int rem = idx & 1023;               // tok*32 + kq
                    float4 v = *(const float4*)&in[gbase + (size_t)bb * TT * HH +
                                                   (size_t)(rem >> 5) * HH + (rem & 31) * 4];
                    *(float4*)&s_in[idx * 4] = v;
                }
            }
            lds_barrier();

            // ---- X GEMM: xi[bb][tok][g-rows] for this window ----
            {
                const int g  = tid & 127;
                const int tq = tid >> 7;                // token quarter [0,4)
                const float* w0p = Wih + (size_t)g * HH;
                const float* w1p = Wih + (size_t)(HH + g) * HH;
                const float* w2p = Wih + (size_t)(2 * HH + g) * HH;
                float acc[BB][3][8];
#pragma unroll
                for (int bb = 0; bb < BB; ++bb)
#pragma unroll
                    for (int i = 0; i < 3; ++i)
#pragma unroll
                        for (int tt = 0; tt < 8; ++tt) acc[bb][i][tt] = 0.0f;
#pragma unroll 2
                for (int kc = 0; kc < 32; ++kc) {
                    float4 wa = *(const float4*)(w0p + kc * 4);
                    float4 wb = *(const float4*)(w1p + kc * 4);
                    float4 wc = *(const float4*)(w2p + kc * 4);
#pragma unroll
                    for (int bb = 0; bb < BB; ++bb)
#pragma unroll
                        for (int tt = 0; tt < 8; ++tt) {
                            float4 sv = *(const float4*)&s_in[bb * (WT * HH) +
                                                              (tq * 8 + tt) * HH + kc * 4];
                            acc[bb][0][tt] = fmaf(wa.x, sv.x, acc[bb][0][tt]);
                            acc[bb][0][tt] = fmaf(wa.y, sv.y, acc[bb][0][tt]);
                            acc[bb][0][tt] = fmaf(wa.z, sv.z, acc[bb][0][tt]);
                            acc[bb][0][tt] = fmaf(wa.w, sv.w, acc[bb][0][tt]);
                            acc[bb][1][tt] = fmaf(wb.x, sv.x, acc[bb][1][tt]);
                            acc[bb][1][tt] = fmaf(wb.y, sv.y, acc[bb][1][tt]);
                            acc[bb][1][tt] = fmaf(wb.z, sv.z, acc[bb][1][tt]);
                            acc[bb][1][tt] = fmaf(wb.w, sv.w, acc[bb][1][tt]);
                            acc[bb][2][tt] = fmaf(wc.x, sv.x, acc[bb][2][tt]);
                            acc[bb][2][tt] = fmaf(wc.y, sv.y, acc[bb][2][tt]);
                            acc[bb][2][tt] = fmaf(wc.z, sv.z, acc[bb][2][tt]);
                            acc[bb][2][tt] = fmaf(wc.w, sv.w, acc[bb][2][tt]);
                        }
                }
#pragma unroll
                for (int bb = 0; bb < BB; ++bb)
#pragma unroll
                    for (int tt = 0; tt < 8; ++tt) {
                        int tok = tq * 8 + tt;
                        s_xi[bb * (WT * G3) + tok * G3 + g]          = acc[bb][0][tt];
                        s_xi[bb * (WT * G3) + tok * G3 + HH + g]     = acc[bb][1][tt];
                        s_xi[bb * (WT * G3) + tok * G3 + 2 * HH + g] = acc[bb][2][tt];
                    }
            }
            lds_barrier();
        }

        // ================= recurrent steps for this window =================
        for (int tw = 0; tw < WT; ++tw) {
            const int t   = w * WT + tw;
            const int cur = t & 1;

            float a00 = 0.f, a01 = 0.f, a02 = 0.f, a10 = 0.f, a11 = 0.f, a12 = 0.f;
            const float* hp0 = &s_h[cur][0][kt][0];
            const float* hp1 = &s_h[cur][1][kt][0];
#pragma unroll
            for (int jj = 0; jj < 32; jj += 4) {
                float4 u = *(const float4*)(hp0 + jj);
                float4 v = *(const float4*)(hp1 + jj);
                a00 = fmaf(wh[0][jj], u.x, a00); a00 = fmaf(wh[0][jj+1], u.y, a00);
                a00 = fmaf(wh[0][jj+2], u.z, a00); a00 = fmaf(wh[0][jj+3], u.w, a00);
                a01 = fmaf(wh[1][jj], u.x, a01); a01 = fmaf(wh[1][jj+1], u.y, a01);
                a01 = fmaf(wh[1][jj+2], u.z, a01); a01 = fmaf(wh[1][jj+3], u.w, a01);
                a02 = fmaf(wh[2][jj], u.x, a02); a02 = fmaf(wh[2][jj+1], u.y, a02);
                a02 = fmaf(wh[2][jj+2], u.z, a02); a02 = fmaf(wh[2][jj+3], u.w, a02);
                a10 = fmaf(wh[0][jj], v.x, a10); a10 = fmaf(wh[0][jj+1], v.y, a10);
                a10 = fmaf(wh[0][jj+2], v.z, a10); a10 = fmaf(wh[0][jj+3], v.w, a10);
                a11 = fmaf(wh[1][jj], v.x, a11); a11 = fmaf(wh[1][jj+1], v.y, a11);
                a11 = fmaf(wh[1][jj+2], v.z, a11); a11 = fmaf(wh[1][jj+3], v.w, a11);
                a12 = fmaf(wh[2][jj], v.x, a12); a12 = fmaf(wh[2][jj+1], v.y, a12);
                a12 = fmaf(wh[2][jj+2], v.z, a12); a12 = fmaf(wh[2][jj+3], v.w, a12);
            }
            a00 += __shfl_xor(a00, 1, 64); a00 += __shfl_xor(a00, 2, 64);
            a01 += __shfl_xor(a01, 1, 64); a01 += __shfl_xor(a01, 2, 64);
            a02 += __shfl_xor(a02, 1, 64); a02 += __shfl_xor(a02, 2, 64);
            a10 += __shfl_xor(a10, 1, 64); a10 += __shfl_xor(a10, 2, 64);
            a11 += __shfl_xor(a11, 1, 64); a11 += __shfl_xor(a11, 2, 64);
            a12 += __shfl_xor(a12, 1, 64); a12 += __shfl_xor(a12, 2, 64);

            if (kt < 2) {   // lane kt==bb finalizes row b0+bb
                const int bb = kt;
                float cr  = (kt == 0) ? a00 : a10;
                float cz  = (kt == 0) ? a01 : a11;
                float cnh = (kt == 0) ? a02 : a12;
                float xr, xz, xn;
                if constexpr (FIRST) {
                    const float* xp = &s_in[bb * (TT * 5) + t * 5];
                    float x0 = xp[0], x1 = xp[1], x2 = xp[2], x3 = xp[3], x4 = xp[4];
                    xr = wx5[0][0]*x0 + wx5[0][1]*x1 + wx5[0][2]*x2 + wx5[0][3]*x3 + wx5[0][4]*x4;
                    xz = wx5[1][0]*x0 + wx5[1][1]*x1 + wx5[1][2]*x2 + wx5[1][3]*x3 + wx5[1][4]*x4;
                    xn = wx5[2][0]*x0 + wx5[2][1]*x1 + wx5[2][2]*x2 + wx5[2][3]*x3 + wx5[2][4]*x4;
                } else {
                    const float* xp = &s_xi[bb * (WT * G3) + tw * G3];
                    xr = xp[gt]; xz = xp[HH + gt]; xn = xp[2 * HH + gt];
                }
                float r = sigmoidf_(xr + cr + br);
                float z = sigmoidf_(xz + cz + bz);
                float n = tanhf_(xn + bxn + r * (cnh + bhn));
                float hp = s_h[cur][bb][gt >> 5][gt & 31];
                float hv = (1.0f - z) * n + z * hp;
                s_h[cur ^ 1][bb][gt >> 5][gt & 31] = hv;
                if constexpr (!LAST)
                    out[((size_t)(b0 + bb) * TT + t) * HH + gt] = hv;
            }
            lds_barrier();   // single per-step barrier (lgkm only)
        }
    }

    if constexpr (LAST) {
        // fused FC: final h is in s_h[0] (cur^1 of t=511)
        if (tid < 128) {
            int bb = tid >> 6, l = tid & 63;
            float h0 = s_h[0][bb][l >> 5][l & 31];
            float h1 = s_h[0][bb][(l >> 5) + 2][l & 31];
            float s = h0 * fcw[l] + h1 * fcw[l + 64];
#pragma unroll
            for (int m = 32; m >= 1; m >>= 1) s += __shfl_xor(s, m, 64);
            if (l == 0) fcout[b0 + bb] = s + fcb[0];
        }
    }
}

extern "C" void kernel_launch(void* const* d_in, const int* in_sizes, int n_in,
                              void* d_out, int out_size, void* d_ws, size_t ws_size,
                              hipStream_t stream) {
    const float* x    = (const float*)d_in[0];
    const float* Wih0 = (const float*)d_in[1];
    const float* Whh0 = (const float*)d_in[2];
    const float* bih0 = (const float*)d_in[3];
    const float* bhh0 = (const float*)d_in[4];
    const float* WihR = (const float*)d_in[5];
    const float* WhhR = (const float*)d_in[6];
    const float* bihR = (const float*)d_in[7];
    const float* bhhR = (const float*)d_in[8];
    const float* fcw  = (const float*)d_in[9];
    const float* fcb  = (const float*)d_in[10];

    float* buf = (float*)d_ws;   // 512*512*128*4 = 134 MB, in-place across layers

    gru_layer<true, false><<<NBLK, NTHR, 0, stream>>>(x, buf, Wih0, Whh0, bih0, bhh0,
                                                      nullptr, nullptr, nullptr);
    gru_layer<false, false><<<NBLK, NTHR, 0, stream>>>(buf, buf, WihR, WhhR, bihR, bhhR,
                                                       nullptr, nullptr, nullptr);
    gru_layer<false, false><<<NBLK, NTHR, 0, stream>>>(buf, buf, WihR + G3 * HH,
                                                       WhhR + G3 * HH, bihR + G3, bhhR + G3,
                                                       nullptr, nullptr, nullptr);
    gru_layer<false, true><<<NBLK, NTHR, 0, stream>>>(buf, buf, WihR + 2 * G3 * HH,
                                                      WhhR + 2 * G3 * HH, bihR + 2 * G3,
                                                      bhhR + 2 * G3, fcw, fcb, (float*)d_out);
}